// Round 3
// baseline (305.045 us; speedup 1.0000x reference)
//
#include <hip/hip_runtime.h>
#include <hip/hip_bf16.h>

typedef __bf16 bf16x8 __attribute__((ext_vector_type(8)));
typedef float  f32x4  __attribute__((ext_vector_type(4)));

#define N_TOT   16384
#define K_TOT   16384
#define HALF_M  ((size_t)128 * 16384)
#define BN      64
#define BK      64
#define NSTEPS  (K_TOT / BK)   // 256

__device__ __forceinline__ unsigned short f2bf(float f) {
    __hip_bfloat16 h = __float2bfloat16(f);
    return __builtin_bit_cast(unsigned short, h);
}

// Swizzled byte offset: 128-B rows, 16-B granules, XOR row&7 into granule idx.
__device__ __forceinline__ int swz(int row, int g) {
    return row * 128 + (((g ^ (row & 7)) & 7) << 4);
}

// One-time T = concat(x0,x1) fp32 -> bf16 into workspace (linear row-major).
__global__ void cvtT_kernel(const float* __restrict__ x0,
                            const float* __restrict__ x1,
                            unsigned short* __restrict__ wsT) {
    size_t i = (size_t)blockIdx.x * blockDim.x + threadIdx.x;  // 0..524287
    size_t e = i * 8;
    const float* src = (e < HALF_M) ? (x0 + e) : (x1 + (e - HALF_M));
    float4 a = ((const float4*)src)[0];
    float4 b = ((const float4*)src)[1];
    union { unsigned short u[8]; uint4 v; } o;
    o.u[0] = f2bf(a.x); o.u[1] = f2bf(a.y); o.u[2] = f2bf(a.z); o.u[3] = f2bf(a.w);
    o.u[4] = f2bf(b.x); o.u[5] = f2bf(b.y); o.u[6] = f2bf(b.z); o.u[7] = f2bf(b.w);
    ((uint4*)wsT)[i] = o.v;
}

// ---- macros: fully static, no lambdas, no runtime buffer indices ----

#define ISSUE(S, k0) do {                                                     \
    if constexpr (USE_WS) {                                                   \
        const uint4* _p = (const uint4*)(arow_w + (k0));                      \
        w##S##_0 = _p[0]; w##S##_1 = _p[1];                                   \
    } else {                                                                  \
        const float4* _p = (const float4*)(arow_f + (k0));                    \
        f##S##_0 = _p[0]; f##S##_1 = _p[1]; f##S##_2 = _p[2]; f##S##_3 = _p[3];\
    }                                                                         \
    wb##S = *(const float4*)(brow + (k0));                                    \
} while (0)

#define STAGE(S, Ab, Bb) do {                                                 \
    if constexpr (USE_WS) {                                                   \
        *(uint4*)((Ab) + aw0) = w##S##_0;                                     \
        *(uint4*)((Ab) + aw1) = w##S##_1;                                     \
    } else {                                                                  \
        union { unsigned short u[8]; uint4 v; } _t0, _t1;                     \
        _t0.u[0]=f2bf(f##S##_0.x); _t0.u[1]=f2bf(f##S##_0.y);                 \
        _t0.u[2]=f2bf(f##S##_0.z); _t0.u[3]=f2bf(f##S##_0.w);                 \
        _t0.u[4]=f2bf(f##S##_1.x); _t0.u[5]=f2bf(f##S##_1.y);                 \
        _t0.u[6]=f2bf(f##S##_1.z); _t0.u[7]=f2bf(f##S##_1.w);                 \
        _t1.u[0]=f2bf(f##S##_2.x); _t1.u[1]=f2bf(f##S##_2.y);                 \
        _t1.u[2]=f2bf(f##S##_2.z); _t1.u[3]=f2bf(f##S##_2.w);                 \
        _t1.u[4]=f2bf(f##S##_3.x); _t1.u[5]=f2bf(f##S##_3.y);                 \
        _t1.u[6]=f2bf(f##S##_3.z); _t1.u[7]=f2bf(f##S##_3.w);                 \
        *(uint4*)((Ab) + aw0) = _t0.v;                                        \
        *(uint4*)((Ab) + aw1) = _t1.v;                                        \
    }                                                                         \
    union { unsigned short u[4]; uint2 v; } _tb;                              \
    _tb.u[0]=f2bf(wb##S.x); _tb.u[1]=f2bf(wb##S.y);                           \
    _tb.u[2]=f2bf(wb##S.z); _tb.u[3]=f2bf(wb##S.w);                           \
    *(uint2*)((Bb) + bw) = _tb.v;                                             \
} while (0)

// Wm=8 x Wn=2 wave grid: wave owns 32M x 32N. 8 ds_read_b128 + 8 MFMA.
#define COMPUTE(Ab, Bb) do {                                                  \
    bf16x8 _b00 = *(const bf16x8*)((Bb) + boff00);                            \
    bf16x8 _b01 = *(const bf16x8*)((Bb) + boff01);                            \
    bf16x8 _b10 = *(const bf16x8*)((Bb) + boff10);                            \
    bf16x8 _b11 = *(const bf16x8*)((Bb) + boff11);                            \
    bf16x8 _a;                                                                \
    _a = *(const bf16x8*)((Ab) + aoff00);                                     \
    acc00 = __builtin_amdgcn_mfma_f32_16x16x32_bf16(_a, _b00, acc00, 0, 0, 0);\
    acc01 = __builtin_amdgcn_mfma_f32_16x16x32_bf16(_a, _b10, acc01, 0, 0, 0);\
    _a = *(const bf16x8*)((Ab) + aoff01);                                     \
    acc00 = __builtin_amdgcn_mfma_f32_16x16x32_bf16(_a, _b01, acc00, 0, 0, 0);\
    acc01 = __builtin_amdgcn_mfma_f32_16x16x32_bf16(_a, _b11, acc01, 0, 0, 0);\
    _a = *(const bf16x8*)((Ab) + aoff10);                                     \
    acc10 = __builtin_amdgcn_mfma_f32_16x16x32_bf16(_a, _b00, acc10, 0, 0, 0);\
    acc11 = __builtin_amdgcn_mfma_f32_16x16x32_bf16(_a, _b10, acc11, 0, 0, 0);\
    _a = *(const bf16x8*)((Ab) + aoff11);                                     \
    acc10 = __builtin_amdgcn_mfma_f32_16x16x32_bf16(_a, _b01, acc10, 0, 0, 0);\
    acc11 = __builtin_amdgcn_mfma_f32_16x16x32_bf16(_a, _b11, acc11, 0, 0, 0);\
} while (0)

// raw barrier: wait own LDS ops, barrier, pin scheduler. VMEM (wave-private
// prefetch regs) deliberately NOT drained -> loads stay in flight.
#define SYNC do {                                                             \
    asm volatile("s_waitcnt lgkmcnt(0)" ::: "memory");                        \
    __builtin_amdgcn_s_barrier();                                             \
    __builtin_amdgcn_sched_barrier(0);                                        \
} while (0)

// GEMM: C[256 x 16384] = T(256x16384,bf16) * W^T(16384x16384,f32->bf16) + b.
// grid 256 (one BN=64 column strip each), 1024 threads = 16 waves (8M x 2N).
template<bool USE_WS>
__global__ __launch_bounds__(1024)
void gemm_kernel(const float* __restrict__ x0, const float* __restrict__ x1,
                 const float* __restrict__ W,  const float* __restrict__ bias,
                 const unsigned short* __restrict__ wsT,
                 float* __restrict__ out)
{
    __shared__ uint4 smem_[(2 * 32768 + 2 * 8192) / 16];   // 80 KiB
    char* const sm = (char*)smem_;
    char* const A0 = sm;                  // A tiles: 256 rows x 128 B
    char* const A1 = sm + 32768;
    char* const B0 = sm + 65536;          // B tiles: 64 rows x 128 B
    char* const B1 = sm + 65536 + 8192;

    const int tid  = threadIdx.x;
    const int lane = tid & 63;
    const int wave = tid >> 6;
    const int wm = wave >> 1;             // 0..7 (32 M rows each)
    const int wn = wave & 1;              // 0..1 (32 N cols each)
    const int n0 = blockIdx.x * BN;

    // staging geometry
    const int ra  = tid >> 2;             // A row 0..255
    const int pa  = tid & 3;              // 32-B chunk of the 128-B row
    const int rbs = tid >> 4;             // B row 0..63
    const int cbs = (tid & 15) * 4;       // f32 col offset

    const unsigned short* arow_w = wsT + (size_t)ra * K_TOT + pa * 16;
    const float* arow_f = ((ra < 128) ? (x0 + (size_t)ra * K_TOT)
                                      : (x1 + (size_t)(ra - 128) * K_TOT)) + pa * 16;
    const float* brow = W + (size_t)(n0 + rbs) * K_TOT + cbs;

    const int aw0 = swz(ra, 2 * pa);
    const int aw1 = swz(ra, 2 * pa + 1);
    const int bw  = rbs * 128 + (((((tid & 15) >> 1) ^ (rbs & 7)) & 7) << 4) + (tid & 1) * 8;

    // compute-side LDS read offsets: aoff<mf><kf>, boff<nf><kf>
    const int aoff00 = swz(wm * 32 +  0 + (lane & 15), 0 + (lane >> 4));
    const int aoff01 = swz(wm * 32 +  0 + (lane & 15), 4 + (lane >> 4));
    const int aoff10 = swz(wm * 32 + 16 + (lane & 15), 0 + (lane >> 4));
    const int aoff11 = swz(wm * 32 + 16 + (lane & 15), 4 + (lane >> 4));
    const int boff00 = swz(wn * 32 +  0 + (lane & 15), 0 + (lane >> 4));
    const int boff01 = swz(wn * 32 +  0 + (lane & 15), 4 + (lane >> 4));
    const int boff10 = swz(wn * 32 + 16 + (lane & 15), 0 + (lane >> 4));
    const int boff11 = swz(wn * 32 + 16 + (lane & 15), 4 + (lane >> 4));

    f32x4 acc00 = {0.f,0.f,0.f,0.f}, acc01 = {0.f,0.f,0.f,0.f};
    f32x4 acc10 = {0.f,0.f,0.f,0.f}, acc11 = {0.f,0.f,0.f,0.f};

    // two named register sets (even / odd K-step) — static, spill-proof
    uint4  w0_0, w0_1, w1_0, w1_1;
    float4 f0_0, f0_1, f0_2, f0_3, f1_0, f1_1, f1_2, f1_3;
    float4 wb0, wb1;

    ISSUE(0, 0);
    ISSUE(1, BK);
    STAGE(0, A0, B0);                     // compiler waits vmcnt for set 0 only
    SYNC;

    for (int kt = 0; kt < NSTEPS; kt += 2) {
        // phase A: compute even buf, stage odd step, prefetch kt+2 (even set)
        if (kt + 2 < NSTEPS) ISSUE(0, (kt + 2) * BK);
        COMPUTE(A0, B0);
        STAGE(1, A1, B1);                 // waits vmcnt for set 1 only
        SYNC;
        // phase B: compute odd buf, stage kt+2, prefetch kt+3 (odd set)
        if (kt + 3 < NSTEPS) ISSUE(1, (kt + 3) * BK);
        COMPUTE(A1, B1);
        if (kt + 2 < NSTEPS) STAGE(0, A0, B0);
        SYNC;
    }

    // epilogue: C/D layout col=lane&15, row=(lane>>4)*4+j
    const int colbase = n0 + wn * 32 + (lane & 15);
    #pragma unroll
    for (int nf = 0; nf < 2; ++nf) {
        const int col = colbase + nf * 16;
        const float bv = bias[col];
        #pragma unroll
        for (int mf = 0; mf < 2; ++mf) {
            const f32x4 a = (nf == 0) ? (mf == 0 ? acc00 : acc10)
                                      : (mf == 0 ? acc01 : acc11);
            #pragma unroll
            for (int j = 0; j < 4; ++j) {
                int r = wm * 32 + mf * 16 + (lane >> 4) * 4 + j;
                float v = a[j] + bv;
                float* o = (r < 128) ? (out + (size_t)r * N_TOT + col)
                                     : (out + HALF_M + (size_t)(r - 128) * N_TOT + col);
                *o = v;
            }
        }
    }
}

extern "C" void kernel_launch(void* const* d_in, const int* in_sizes, int n_in,
                              void* d_out, int out_size, void* d_ws, size_t ws_size,
                              hipStream_t stream) {
    const float* x0 = (const float*)d_in[0];
    const float* x1 = (const float*)d_in[1];
    const float* W  = (const float*)d_in[2];
    const float* b  = (const float*)d_in[3];
    float* out = (float*)d_out;

    const size_t wsT_bytes = (size_t)256 * 16384 * sizeof(unsigned short);  // 8.4 MB
    if (ws_size >= wsT_bytes) {
        unsigned short* wsT = (unsigned short*)d_ws;
        cvtT_kernel<<<2048, 256, 0, stream>>>(x0, x1, wsT);
        gemm_kernel<true><<<256, 1024, 0, stream>>>(x0, x1, W, b, wsT, out);
    } else {
        gemm_kernel<false><<<256, 1024, 0, stream>>>(x0, x1, W, b, nullptr, out);
    }
}